// Round 11
// baseline (46.298 us; speedup 1.0000x reference)
//
#include <hip/hip_runtime.h>
#include <stdint.h>

typedef short bf16x8 __attribute__((ext_vector_type(8)));
typedef float f32x4 __attribute__((ext_vector_type(4)));

#define NROWS 8192
#define DIM   128
// sqrt(10/ln2): dot of scaled z gives 10*cos/ln2, so exp2(dot)=exp(10*cos)
#define ZSCALE 3.7982824f
#define LN2F  0.6931471805599453f

// zf layout (fragment-linear): chunk (b, ks) = 1KB at (b*4+ks)*1024 bytes;
// lane l (g=l>>4, q=l&15) holds z[b*16+q][ks*32+g*8 .. +8] as bf16x8.

__device__ __forceinline__ unsigned short f32_to_bf16_bits(float x) {
  union { float f; uint32_t u; } v; v.f = x;
  uint32_t r = v.u + 0x7FFFu + ((v.u >> 16) & 1u);  // RNE
  return (unsigned short)(r >> 16);
}

// K0: Wtf = W in B-fragment order; zero sumexp/topacc.
__global__ __launch_bounds__(256) void k_wprep(const float* __restrict__ W,
                                               unsigned short* __restrict__ Wtf,
                                               float* __restrict__ sumexp,
                                               float* __restrict__ topacc) {
  const int idx = blockIdx.x * 256 + threadIdx.x;  // grid 64 -> 16384
  if (idx < 2048) {
    const int l = idx & 63, chunk = idx >> 6;  // chunk = tj*4+ks
    const int tj = chunk >> 2, ks = chunk & 3, g = l >> 4, q = l & 15;
    const float* wp = W + (size_t)(ks * 32 + g * 8) * DIM + tj * 16 + q;
    bf16x8 o;
#pragma unroll
    for (int e = 0; e < 8; ++e) o[e] = (short)f32_to_bf16_bits(wp[(size_t)e * DIM]);
    *(bf16x8*)(Wtf + (size_t)idx * 8) = o;
  }
  if (idx < NROWS) sumexp[idx] = 0.f;
  if (idx == 0) topacc[0] = 0.f;
}

// K1: zf = fragment-order bf16( ZSCALE * normalize(anchor @ W + bias) ).
// 512 blocks x 4 waves; wave wv computes K-slice ks=wv, LDS reduce,
// normalize + fragment-order store.
__global__ __launch_bounds__(256) void k_proj_norm(
    const float* __restrict__ anchor, const unsigned short* __restrict__ Wtf,
    const float* __restrict__ bias, unsigned short* __restrict__ zf) {
  __shared__ float part[4][16][132];  // padded cols
  const int t = threadIdx.x;
  const int wv = t >> 6, l = t & 63, g = l >> 4, q = l & 15;
  const int rb = blockIdx.x * 16;

  // A frag (K-slice wv): anchor[rb+q][wv*32+g*8 .. +8]
  const float* ap = anchor + (size_t)(rb + q) * DIM + wv * 32 + g * 8;
  const f32x4 a0 = *(const f32x4*)ap, a1 = *(const f32x4*)(ap + 4);
  bf16x8 a;
#pragma unroll
  for (int e = 0; e < 4; ++e) {
    a[e] = (short)f32_to_bf16_bits(a0[e]);
    a[4 + e] = (short)f32_to_bf16_bits(a1[e]);
  }

  f32x4 acc[8];
#pragma unroll
  for (int tj = 0; tj < 8; ++tj) acc[tj] = (f32x4){0.f, 0.f, 0.f, 0.f};
#pragma unroll
  for (int tj = 0; tj < 8; ++tj) {
    const bf16x8 b = *(const bf16x8*)(Wtf + (size_t)((tj * 4 + wv) * 64 + l) * 8);
    acc[tj] = __builtin_amdgcn_mfma_f32_16x16x32_bf16(a, b, acc[tj], 0, 0, 0);
  }

  // partials: C layout col=q,row=4g+r -> part[wv][4g+r][tj*16+q]
#pragma unroll
  for (int tj = 0; tj < 8; ++tj)
#pragma unroll
    for (int r = 0; r < 4; ++r) part[wv][4 * g + r][tj * 16 + q] = acc[tj][r];
  __syncthreads();

  // reduce k-slices + bias + normalize + fragment-order store
  const int row = t >> 4, c = t & 15;  // c = 8-col chunk
  float v[8];
#pragma unroll
  for (int e = 0; e < 8; ++e) v[e] = bias[c * 8 + e];
#pragma unroll
  for (int s = 0; s < 4; ++s) {
    const f32x4 p0 = *(const f32x4*)&part[s][row][c * 8];
    const f32x4 p1 = *(const f32x4*)&part[s][row][c * 8 + 4];
#pragma unroll
    for (int e = 0; e < 4; ++e) {
      v[e] += p0[e];
      v[4 + e] += p1[e];
    }
  }
  float ss = 0.f;
#pragma unroll
  for (int e = 0; e < 8; ++e) ss += v[e] * v[e];
#pragma unroll
  for (int m = 1; m < 16; m <<= 1) ss += __shfl_xor(ss, m, 64);
  const float inv = ZSCALE / fmaxf(sqrtf(ss), 1e-12f);

  bf16x8 o;
#pragma unroll
  for (int e = 0; e < 8; ++e) o[e] = (short)f32_to_bf16_bits(v[e] * inv);
  const int ks = c >> 2, gg = c & 3;
  *(bf16x8*)(zf + (size_t)(((blockIdx.x * 4 + ks) * 64) + gg * 16 + row) * 8) = o;
}

// K2: fused Z @ Z^T -> exp2 -> row+col sums, upper-triangular 256x256 tiles
// (E symmetric). 4 waves x 64 i-rows; B-panels streamed through a ring-4
// register prefetch (group k+4 issued when group k is consumed -> ~3 groups
// of compute cover the L2/L3 load latency; no barriers, counted vmcnt by
// register dependency). Col-sums go to LDS via ds_add_f32 (fire-and-forget),
// scattered to global once per block. MODE 0: diag; 1: off; 2: off+pos.
template <int MODE>
__device__ __forceinline__ void simloss_body(
    const unsigned short* __restrict__ zf, float* __restrict__ sumexp,
    float* __restrict__ topacc, float* __restrict__ lds_col, const int r0,
    const int cb, const int t, const int l, const int g, const int q) {
  // A frags: afr[ti][ks] for rows r0+ti*16+q (lane-linear, 64 VGPR)
  bf16x8 afr[4][4];
#pragma unroll
  for (int ti = 0; ti < 4; ++ti)
#pragma unroll
    for (int ks = 0; ks < 4; ++ks)
      afr[ti][ks] = *(const bf16x8*)(
          zf + (size_t)((((r0 >> 4) + ti) * 4 + ks) * 512 + l * 8));

  float sums[4][4];
#pragma unroll
  for (int ti = 0; ti < 4; ++ti)
#pragma unroll
    for (int r = 0; r < 4; ++r) sums[ti][r] = 0.f;
  float topv = 0.f;
  const int posr = r0 + 4096;  // MODE 2 only (igrp<16 -> no wrap)

  // ring-4 B prefetch: ring[s][ks] holds group (k: k&3==s) of 16 cols
  bf16x8 ring[4][4];
#define LOADG(slot, gi)                                                     \
  {                                                                         \
    const int bcol = (cb >> 4) + (gi);                                      \
    _Pragma("unroll") for (int ks = 0; ks < 4; ++ks) ring[slot][ks] =       \
        *(const bf16x8*)(zf + (size_t)((bcol * 4 + ks) * 512 + l * 8));     \
  }

#pragma unroll
  for (int s = 0; s < 4; ++s) LOADG(s, s);  // prologue: groups 0..3 in flight

#pragma unroll
  for (int k = 0; k < 16; ++k) {
    const int slot = k & 3;  // unroll-static
    // ---- compute group k ----
    f32x4 acc[4];
#pragma unroll
    for (int ti = 0; ti < 4; ++ti) acc[ti] = (f32x4){0.f, 0.f, 0.f, 0.f};
#pragma unroll
    for (int ti = 0; ti < 4; ++ti)
#pragma unroll
      for (int ks = 0; ks < 4; ++ks)
        acc[ti] = __builtin_amdgcn_mfma_f32_16x16x32_bf16(
            afr[ti][ks], ring[slot][ks], acc[ti], 0, 0, 0);

    const int c0 = cb + k * 16;
    int dgti = -1, psti = -1;
    if (MODE == 0) {
      const int dgo = c0 - r0;
      dgti = ((unsigned)dgo < 64u) ? (dgo >> 4) : -1;
    }
    if (MODE == 2) {
      const int pso = c0 - posr;
      psti = ((unsigned)pso < 64u) ? (pso >> 4) : -1;
    }
    float cs = 0.f;
#pragma unroll
    for (int ti = 0; ti < 4; ++ti)
#pragma unroll
      for (int r = 0; r < 4; ++r) {
        const float d = acc[ti][r];
        float e = __builtin_amdgcn_exp2f(d);
        if (MODE == 0 && ti == dgti && q == 4 * g + r) e = 0.f;    // j == i
        if (MODE == 2 && ti == psti && q == 4 * g + r) topv += d;  // pos pair
        sums[ti][r] += e;
        if (MODE != 0) cs += e;
      }
    if (MODE != 0) atomicAdd(&lds_col[k * 16 + q], cs);  // ds_add_f32

    // ---- refill slot with group k+4 (3-group latency cover) ----
    if (k + 4 < 16) LOADG(slot, k + 4);
  }
#undef LOADG

  // row-sum reduce across the 16 q-lanes
#pragma unroll
  for (int ti = 0; ti < 4; ++ti)
#pragma unroll
    for (int r = 0; r < 4; ++r) {
#pragma unroll
      for (int m = 1; m < 16; m <<= 1)
        sums[ti][r] += __shfl_xor(sums[ti][r], m, 64);
    }
  if (q == 0) {
#pragma unroll
    for (int ti = 0; ti < 4; ++ti)
#pragma unroll
      for (int r = 0; r < 4; ++r)
        atomicAdd(&sumexp[r0 + ti * 16 + 4 * g + r], sums[ti][r]);
  }

  if (MODE != 0) {  // col-scatter: one global atomic per column per block
    __syncthreads();
    atomicAdd(&sumexp[cb + t], lds_col[t]);
  }

  if (MODE == 2) {  // each pair element counts for both rows' tops
#pragma unroll
    for (int m = 1; m < 64; m <<= 1) topv += __shfl_xor(topv, m, 64);
    if (l == 0) atomicAdd(topacc, 2.f * topv);
  }
}

// grid = 528 upper-triangular (igrp, jbi>=igrp) 256x256 tiles; 256 threads.
// No min-waves in launch_bounds (R9: (512,4) capped VGPR at 64 -> 217 MB of
// scratch spill). Allocator picks ~190 VGPR -> 2 waves/SIMD, zero spill.
__global__ __launch_bounds__(256) void k_simloss(
    const unsigned short* __restrict__ zf, float* __restrict__ sumexp,
    float* __restrict__ topacc) {
  __shared__ float lds_col[256];
  const int t = threadIdx.x;
  const int wv = t >> 6, l = t & 63, g = l >> 4, q = l & 15;
  lds_col[t] = 0.f;
  __syncthreads();

  int rem = (int)blockIdx.x, igrp = 0;
  while (rem >= 32 - igrp) { rem -= 32 - igrp; ++igrp; }  // uniform SALU
  const int jbi = igrp + rem;
  const int r0 = igrp * 256 + wv * 64;  // wave's 64 i-rows
  const int cb = jbi * 256;             // block's 256 j-cols
  if (igrp == jbi)
    simloss_body<0>(zf, sumexp, topacc, lds_col, r0, cb, t, l, g, q);
  else if (jbi == igrp + 16)
    simloss_body<2>(zf, sumexp, topacc, lds_col, r0, cb, t, l, g, q);
  else
    simloss_body<1>(zf, sumexp, topacc, lds_col, r0, cb, t, l, g, q);
}

// K3: loss = LN2 * (sum_i log2(bottom_i) - topacc) / (b-1)
__global__ __launch_bounds__(1024) void k_final(const float* __restrict__ sumexp,
                                                const float* __restrict__ topacc,
                                                float* __restrict__ out) {
  __shared__ float red[16];
  const int t = threadIdx.x;
  float s = 0.f;
  for (int r = t; r < NROWS; r += 1024) s += __log2f(sumexp[r]);
#pragma unroll
  for (int m = 1; m < 64; m <<= 1) s += __shfl_xor(s, m, 64);
  if ((t & 63) == 0) red[t >> 6] = s;
  __syncthreads();
  if (t == 0) {
    float S1 = 0.f;
#pragma unroll
    for (int i = 0; i < 16; ++i) S1 += red[i];
    out[0] = LN2F * (S1 - topacc[0]) * (1.0f / (float)(NROWS - 1));
  }
}

extern "C" void kernel_launch(void* const* d_in, const int* in_sizes, int n_in,
                              void* d_out, int out_size, void* d_ws, size_t ws_size,
                              hipStream_t stream) {
  const float* anchor = (const float*)d_in[0];
  const float* W = (const float*)d_in[1];
  const float* bias = (const float*)d_in[2];
  float* out = (float*)d_out;

  char* ws = (char*)d_ws;
  unsigned short* zf = (unsigned short*)ws;                        // 2 MB fragment-order z
  float* sumexp = (float*)(ws + (size_t)2 * 1024 * 1024);          // 32 KB
  float* topacc = (float*)(ws + (size_t)2 * 1024 * 1024 + 32768);  // 4 B
  unsigned short* Wtf = (unsigned short*)(ws + (size_t)2 * 1024 * 1024 + 36864); // 32 KB

  k_wprep<<<dim3(64), dim3(256), 0, stream>>>(W, Wtf, sumexp, topacc);
  k_proj_norm<<<dim3(NROWS / 16), dim3(256), 0, stream>>>(anchor, Wtf, bias, zf);
  k_simloss<<<dim3(528), dim3(256), 0, stream>>>(zf, sumexp, topacc);
  k_final<<<dim3(1), dim3(1024), 0, stream>>>(sumexp, topacc, out);
}